// Round 8
// baseline (324.287 us; speedup 1.0000x reference)
//
#include <hip/hip_runtime.h>
#include <stdint.h>

#define N_BATCH 32
#define CHN     256
#define HW      56
#define HP      58

// xpad layout (uint4 "cells" of 4 u32 = 128 channel-bits):
//   cell(n, hp, h, wp) = ((n*58 + hp)*2 + h)*58 + wp,  h = channel-half
#define XPAD_CELLS (N_BATCH * HP * 2 * HP)   // 215,296 cells
#define XPAD_U32   (XPAD_CELLS * 4)

// ---------------- fused prep (UNCHANGED from verified baseline) -------------
__global__ __launch_bounds__(256) void prep_kernel(const float* __restrict__ x,
                                                   const float* __restrict__ wsrc,
                                                   uint32_t* __restrict__ xpad,
                                                   uint32_t* __restrict__ wbits,
                                                   int* __restrict__ wpop) {
    __shared__ int part[9][4];
    int bid  = blockIdx.x;
    int t    = threadIdx.x;
    int lane = t & 63;

    if (bid < 784) {
        int tid = bid * 256 + t;          // 0..200703
        int n   = tid / 6272;             // 6272 = 3136 px * 2 halves
        int rem = tid - n * 6272;
        int hf  = rem / 3136;             // channel half
        int pq  = rem - hf * 3136;        // pixel in plane; lane-consecutive

        const float* src = x + ((size_t)(n * 256 + hf * 128)) * 3136 + pq;
        uint32_t b0 = 0, b1 = 0, b2 = 0, b3 = 0;
#pragma unroll
        for (int g = 0; g < 8; g++) {
            float v[16];
#pragma unroll
            for (int i = 0; i < 16; i++) v[i] = src[(size_t)(g * 16 + i) * 3136];
#pragma unroll
            for (int i = 0; i < 16; i++) {
                int c = g * 16 + i;       // 0..127 within half
                uint32_t b = v[i] > 0.0f ? 1u : 0u;
                if ((c >> 5) == 0) b0 |= b << (c & 31);
                else if ((c >> 5) == 1) b1 |= b << (c & 31);
                else if ((c >> 5) == 2) b2 |= b << (c & 31);
                else b3 |= b << (c & 31);
            }
        }
        int h = pq / 56;
        int w = pq - h * 56;
        uint32_t cell = ((uint32_t)(n * HP + h + 1) * 2 + hf) * HP + (w + 1);
        ((uint4*)xpad)[cell] = make_uint4(b0, b1, b2, b3);
    } else if (bid < 841) {
        int u = (bid - 784) * 256 + t;
        if (u < 14592) {
            int p = u / 228;
            int e = u - p * 228;
            int n = p >> 1, h = p & 1;
            int hp, wp;
            if (e < 58)       { hp = 0;       wp = e;       }
            else if (e < 116) { hp = 57;      wp = e - 58;  }
            else if (e < 172) { hp = e - 115; wp = 0;       }
            else              { hp = e - 171; wp = 57;      }
            uint32_t cell = ((uint32_t)(n * HP + hp) * 2 + h) * HP + wp;
            ((uint4*)xpad)[cell] = make_uint4(0u, 0u, 0u, 0u);
        }
    } else {
        int o  = bid - 841;
        int wv = t >> 6;
        const float* p = wsrc + ((size_t)o * 256 + t) * 9;
        float v[9];
#pragma unroll
        for (int tap = 0; tap < 9; tap++) v[tap] = p[tap];
#pragma unroll
        for (int tap = 0; tap < 9; tap++) {
            unsigned long long m = __ballot(v[tap] > 0.0f);
            if (lane == 0) {
                wbits[(size_t)(o * 9 + tap) * 8 + 2 * wv]     = (uint32_t)m;
                wbits[(size_t)(o * 9 + tap) * 8 + 2 * wv + 1] = (uint32_t)(m >> 32);
                part[tap][wv] = __builtin_popcountll(m);
            }
        }
        __syncthreads();
        if (t < 9) wpop[o * 9 + t] = part[t][0] + part[t][1] + part[t][2] + part[t][3];
    }
}

// ---------------- binary conv: 2 output channels per lane -------------------
// Round-5 structure + VOLATILE register pin on WA/WB/papack.
// History: R5 (no pin) -> compiler SANK the 144 weight loads into the pixel
// loop (VGPR_Count=104 < 144 W regs; ~7 GB of L1 re-reads; 142us).
// R7 (non-volatile pin) -> LLVM sank/duplicated the movable asm too
// (VGPR=96, 158us). volatile asm cannot be deleted, duplicated, or sunk:
// after the pin, W values are asm outputs, not re-derivable from memory.
// Spill tripwire: VGPR~high + inflated WRITE/FETCH => scratch (rounds 2/3).
// __launch_bounds__ min-waves MUST stay 2 (4 forces <=128 VGPR -> spill).
__global__ __launch_bounds__(256, 2)
void conv_kernel(const uint32_t* __restrict__ xpad,
                 const uint32_t* __restrict__ wbits,
                 const int* __restrict__ wpop,
                 float* __restrict__ out) {
    __shared__ uint4 sx[3 * 2 * HP];          // 348 cells = 5,568 B
    __shared__ short obuf[256 * 57];          // 29,184 B (57 coprime w/ 32 banks)

    int t    = threadIdx.x;
    int lane = t & 63;
    int wv   = t >> 6;
    int og   = wv & 1;                        // o-group
    int pH   = wv >> 1;                       // pixel half
    int h    = blockIdx.x;                    // output row 0..55
    int n    = blockIdx.y;

    // stage padded input rows h..h+2 (348 contiguous cells)
    const uint4* xg = (const uint4*)xpad + ((size_t)n * HP + h) * (2 * HP);
    for (int i = t; i < 3 * 2 * HP; i += 256) sx[i] = xg[i];

    // per-lane weights for o1 = og*64+lane and o2 = o1+128 (36 uint4 = 144 VGPR)
    int o1 = og * 64 + lane;
    const uint4* w1p = (const uint4*)(wbits + (size_t)o1 * 72);
    const uint4* w2p = (const uint4*)(wbits + (size_t)(o1 + 128) * 72);
    uint4 WA[18], WB[18];
#pragma unroll
    for (int i = 0; i < 18; i++) WA[i] = w1p[i];
#pragma unroll
    for (int i = 0; i < 18; i++) WB[i] = w2p[i];

    // wpop for both o's, packed two-per-u32 (values <= 256 fit 16 bits)
    const int* pp1 = wpop + (size_t)o1 * 9;
    const int* pp2 = wpop + (size_t)(o1 + 128) * 9;
    uint32_t papack[9];
#pragma unroll
    for (int i = 0; i < 9; i++)
        papack[i] = (uint32_t)pp1[i] | ((uint32_t)pp2[i] << 16);

    // ---- PIN (volatile: immovable, non-duplicable, non-deletable) ----
#pragma unroll
    for (int i = 0; i < 18; i++) {
        asm volatile("" : "+v"(WA[i].x), "+v"(WA[i].y), "+v"(WA[i].z), "+v"(WA[i].w));
        asm volatile("" : "+v"(WB[i].x), "+v"(WB[i].y), "+v"(WB[i].z), "+v"(WB[i].w));
    }
#pragma unroll
    for (int i = 0; i < 9; i++)
        asm volatile("" : "+v"(papack[i]));

    __syncthreads();

    short* ob1 = obuf + o1 * 57;
    short* ob2 = obuf + (o1 + 128) * 57;
    bool hedge = (h == 0) | (h == 55);
    int w0 = pH * 28;

#pragma unroll 1
    for (int wi = 0; wi < 28; wi++) {
        int w = w0 + wi;
        const uint4* cb = sx + w;             // wave-uniform base; imm offsets
        int a0 = 0, a1 = 0, a2 = 0, a3 = 0;   // o1 chains
        int b0 = 0, b1 = 0, b2 = 0, b3 = 0;   // o2 chains
#pragma unroll
        for (int dw = 0; dw < 3; dw++)
#pragma unroll
            for (int rr = 0; rr < 6; rr++) {  // rr = r*2+hf
                uint4 xc = cb[rr * HP + dw];  // ONE broadcast read, EIGHT uses
                uint4 wa = WA[((rr >> 1) * 3 + dw) * 2 + (rr & 1)];
                uint4 wb = WB[((rr >> 1) * 3 + dw) * 2 + (rr & 1)];
                a0 += __builtin_popcount(xc.x ^ wa.x);
                a1 += __builtin_popcount(xc.y ^ wa.y);
                a2 += __builtin_popcount(xc.z ^ wa.z);
                a3 += __builtin_popcount(xc.w ^ wa.w);
                b0 += __builtin_popcount(xc.x ^ wb.x);
                b1 += __builtin_popcount(xc.y ^ wb.y);
                b2 += __builtin_popcount(xc.z ^ wb.z);
                b3 += __builtin_popcount(xc.w ^ wb.w);
            }
        int va = 2304 - 2 * ((a0 + a1) + (a2 + a3));
        int vb = 2304 - 2 * ((b0 + b1) + (b2 + b3));
        if (hedge | (w == 0) | (w == 55)) {   // wave-uniform branch
            int ca = 0, cc = 0;
#pragma unroll
            for (int dh = 0; dh < 3; dh++)
#pragma unroll
                for (int dw = 0; dw < 3; dw++)
                    if ((unsigned)(h + dh - 1) >= 56u || (unsigned)(w + dw - 1) >= 56u) {
                        uint32_t pk = papack[dh * 3 + dw];
                        ca += 256 - 2 * (int)(pk & 0xffffu);
                        cc += 256 - 2 * (int)(pk >> 16);
                    }
            va -= ca;
            vb -= cc;
        }
        ob1[w] = (short)va;
        ob2[w] = (short)vb;
    }

    __syncthreads();                          // obuf rows cross pixel-half waves

    // drain: wave wv drains o in [wv*64, wv*64+64); lane = w (coalesced rows)
    if (lane < 56) {
        const short* obw = obuf + (wv * 64) * 57;
        float* orow = out + (((size_t)n * 256 + wv * 64) * 56 + h) * 56 + lane;
#pragma unroll 8
        for (int o2 = 0; o2 < 64; o2++)
            orow[(size_t)o2 * 3136] = (float)obw[o2 * 57 + lane];
    }
}

extern "C" void kernel_launch(void* const* d_in, const int* in_sizes, int n_in,
                              void* d_out, int out_size, void* d_ws, size_t ws_size,
                              hipStream_t stream) {
    const float* x    = (const float*)d_in[0];
    const float* wsrc = (const float*)d_in[1];
    float* out = (float*)d_out;

    uint32_t* xpad  = (uint32_t*)d_ws;                    // 3.44 MB
    uint32_t* wbits = xpad + XPAD_U32;                    // 18432 u32
    int*      wpop  = (int*)(wbits + 256 * 9 * 8);        // 2304 int

    prep_kernel<<<1097, 256, 0, stream>>>(x, wsrc, xpad, wbits, wpop);
    conv_kernel<<<dim3(HW, N_BATCH), 256, 0, stream>>>(xpad, wbits, wpop, out);
}

// Round 9
// 310.191 us; speedup vs baseline: 1.0454x; 1.0454x over previous
//
#include <hip/hip_runtime.h>
#include <stdint.h>

#define N_BATCH 32
#define CHN     256
#define HW      56
#define HP      58

// xpad layout (uint4 "cells" of 4 u32 = 128 channel-bits):
//   cell(n, hp, h, wp) = ((n*58 + hp)*2 + h)*58 + wp,  h = channel-half
#define XPAD_CELLS (N_BATCH * HP * 2 * HP)   // 215,296 cells
#define XPAD_U32   (XPAD_CELLS * 4)

// ---------------- fused prep (UNCHANGED from verified baseline) -------------
__global__ __launch_bounds__(256) void prep_kernel(const float* __restrict__ x,
                                                   const float* __restrict__ wsrc,
                                                   uint32_t* __restrict__ xpad,
                                                   uint32_t* __restrict__ wbits,
                                                   int* __restrict__ wpop) {
    __shared__ int part[9][4];
    int bid  = blockIdx.x;
    int t    = threadIdx.x;
    int lane = t & 63;

    if (bid < 784) {
        int tid = bid * 256 + t;          // 0..200703
        int n   = tid / 6272;             // 6272 = 3136 px * 2 halves
        int rem = tid - n * 6272;
        int hf  = rem / 3136;             // channel half
        int pq  = rem - hf * 3136;        // pixel in plane; lane-consecutive

        const float* src = x + ((size_t)(n * 256 + hf * 128)) * 3136 + pq;
        uint32_t b0 = 0, b1 = 0, b2 = 0, b3 = 0;
#pragma unroll
        for (int g = 0; g < 8; g++) {
            float v[16];
#pragma unroll
            for (int i = 0; i < 16; i++) v[i] = src[(size_t)(g * 16 + i) * 3136];
#pragma unroll
            for (int i = 0; i < 16; i++) {
                int c = g * 16 + i;       // 0..127 within half
                uint32_t b = v[i] > 0.0f ? 1u : 0u;
                if ((c >> 5) == 0) b0 |= b << (c & 31);
                else if ((c >> 5) == 1) b1 |= b << (c & 31);
                else if ((c >> 5) == 2) b2 |= b << (c & 31);
                else b3 |= b << (c & 31);
            }
        }
        int h = pq / 56;
        int w = pq - h * 56;
        uint32_t cell = ((uint32_t)(n * HP + h + 1) * 2 + hf) * HP + (w + 1);
        ((uint4*)xpad)[cell] = make_uint4(b0, b1, b2, b3);
    } else if (bid < 841) {
        int u = (bid - 784) * 256 + t;
        if (u < 14592) {
            int p = u / 228;
            int e = u - p * 228;
            int n = p >> 1, h = p & 1;
            int hp, wp;
            if (e < 58)       { hp = 0;       wp = e;       }
            else if (e < 116) { hp = 57;      wp = e - 58;  }
            else if (e < 172) { hp = e - 115; wp = 0;       }
            else              { hp = e - 171; wp = 57;      }
            uint32_t cell = ((uint32_t)(n * HP + hp) * 2 + h) * HP + wp;
            ((uint4*)xpad)[cell] = make_uint4(0u, 0u, 0u, 0u);
        }
    } else {
        int o  = bid - 841;
        int wv = t >> 6;
        const float* p = wsrc + ((size_t)o * 256 + t) * 9;
        float v[9];
#pragma unroll
        for (int tap = 0; tap < 9; tap++) v[tap] = p[tap];
#pragma unroll
        for (int tap = 0; tap < 9; tap++) {
            unsigned long long m = __ballot(v[tap] > 0.0f);
            if (lane == 0) {
                wbits[(size_t)(o * 9 + tap) * 8 + 2 * wv]     = (uint32_t)m;
                wbits[(size_t)(o * 9 + tap) * 8 + 2 * wv + 1] = (uint32_t)(m >> 32);
                part[tap][wv] = __builtin_popcountll(m);
            }
        }
        __syncthreads();
        if (t < 9) wpop[o * 9 + t] = part[t][0] + part[t][1] + part[t][2] + part[t][3];
    }
}

// ---------------- binary conv: hf-split waves, sliding X window -------------
// Lesson of R5/R7/R8: the allocator targets <=128 VGPR when LDS permits
// 4 blocks/CU; any design needing more gets its weights sunk to reloads
// (R5: VGPR 104, 142us) regardless of asm pins (R7/R8: VGPR 96, 158us).
// So: shrink per-thread need to ~100 regs. Block = (h, n, o-half); wave wv:
// hf = wv>>1 (channel half), og = wv&1; lane owns ONE o = oh*128+og*64+lane.
// W: 9 uint4 (36 regs). X: 3-col sliding window, 9 uint4 (36 regs),
// 3 broadcast ds_read_b128 per pixel (was 18). hf0/hf1 write int16 partials
// (1152-2*acc; hf0 also carries the full edge correction) to separate obuf
// halves; drain sums. ~100 regs -> no sinking; LDS 34.75KB -> 4 blocks/CU.
__global__ __launch_bounds__(256, 2)
void conv_kernel(const uint32_t* __restrict__ xpad,
                 const uint32_t* __restrict__ wbits,
                 const int* __restrict__ wpop,
                 float* __restrict__ out) {
    __shared__ uint4 sx[3 * 2 * HP];          // 348 cells = 5,568 B
    __shared__ short obuf[2][128][57];        // 29,184 B (57 coprime w/ 32 banks)

    int t    = threadIdx.x;
    int lane = t & 63;
    int wv   = t >> 6;
    int hf   = wv >> 1;                       // channel half (wave-uniform)
    int og   = wv & 1;                        // o-group within the half
    int h    = blockIdx.x;                    // output row 0..55
    int n    = blockIdx.y;
    int oh   = blockIdx.z;                    // o-half: o in [oh*128, oh*128+128)

    // stage padded input rows h..h+2 (348 contiguous cells, both hf halves)
    const uint4* xg = (const uint4*)xpad + ((size_t)n * HP + h) * (2 * HP);
    for (int i = t; i < 3 * 2 * HP; i += 256) sx[i] = xg[i];

    // per-lane: one o, one channel half -> 9 uint4 of W (36 VGPR)
    int ol = og * 64 + lane;                  // 0..127 within the o-half
    int o  = oh * 128 + ol;
    uint4 W[9];
#pragma unroll
    for (int tap = 0; tap < 9; tap++)
        W[tap] = *(const uint4*)(wbits + ((size_t)o * 9 + tap) * 8 + hf * 4);

    int pa[9];                                // full-256 popcounts; hf0 only
    if (hf == 0) {
        const int* wpa = wpop + (size_t)o * 9;
#pragma unroll
        for (int i = 0; i < 9; i++) pa[i] = wpa[i];
    }

    __syncthreads();

    short* ob  = &obuf[hf][ol][0];
    bool hedge = (h == 0) | (h == 55);

    // column c of my hf: rows r=0..2 -> sx[(r*2+hf)*HP + c]; broadcast reads
#define LOADCOL(X, c)                                                          \
    do {                                                                       \
        _Pragma("unroll")                                                      \
        for (int r = 0; r < 3; r++) X[r] = sx[(r * 2 + hf) * HP + (c)];        \
    } while (0)

    // pixel w from columns P(=w), Q(=w+1), R(=w+2); W[r*3+dw]
#define COMPUTE(P, Q, R, wpx)                                                  \
    do {                                                                       \
        int a0 = 0, a1 = 0, a2 = 0, a3 = 0;                                    \
        _Pragma("unroll")                                                      \
        for (int r = 0; r < 3; r++) {                                          \
            uint4 xa = P[r], wa = W[r * 3 + 0];                                \
            a0 += __builtin_popcount(xa.x ^ wa.x);                             \
            a1 += __builtin_popcount(xa.y ^ wa.y);                             \
            a2 += __builtin_popcount(xa.z ^ wa.z);                             \
            a3 += __builtin_popcount(xa.w ^ wa.w);                             \
            uint4 xb = Q[r], wb = W[r * 3 + 1];                                \
            a0 += __builtin_popcount(xb.x ^ wb.x);                             \
            a1 += __builtin_popcount(xb.y ^ wb.y);                             \
            a2 += __builtin_popcount(xb.z ^ wb.z);                             \
            a3 += __builtin_popcount(xb.w ^ wb.w);                             \
            uint4 xc = R[r], wc = W[r * 3 + 2];                                \
            a0 += __builtin_popcount(xc.x ^ wc.x);                             \
            a1 += __builtin_popcount(xc.y ^ wc.y);                             \
            a2 += __builtin_popcount(xc.z ^ wc.z);                             \
            a3 += __builtin_popcount(xc.w ^ wc.w);                             \
        }                                                                      \
        int vp = 1152 - 2 * ((a0 + a1) + (a2 + a3));                           \
        int wq = (wpx);                                                        \
        if (hf == 0) {                        /* full correction on hf0 */     \
            if (hedge | (wq == 0) | (wq == 55)) {                              \
                int ca = 0;                                                    \
                _Pragma("unroll")                                              \
                for (int dh = 0; dh < 3; dh++)                                 \
                    _Pragma("unroll")                                          \
                    for (int dw = 0; dw < 3; dw++)                             \
                        if ((unsigned)(h + dh - 1) >= 56u ||                   \
                            (unsigned)(wq + dw - 1) >= 56u)                    \
                            ca += 256 - 2 * pa[dh * 3 + dw];                   \
                vp -= ca;                                                      \
            }                                                                  \
        }                                                                      \
        ob[wq] = (short)vp;                                                    \
    } while (0)

    uint4 XA[3], XB[3], XC[3];
    LOADCOL(XA, 0);
    LOADCOL(XB, 1);

    int w = 0;
#pragma unroll 1
    for (int i = 0; i < 18; i++) {            // pixels 0..53, period-3 rotation
        LOADCOL(XC, w + 2); COMPUTE(XA, XB, XC, w);
        LOADCOL(XA, w + 3); COMPUTE(XB, XC, XA, w + 1);
        LOADCOL(XB, w + 4); COMPUTE(XC, XA, XB, w + 2);
        w += 3;
    }
    // tail: pixels 54, 55 (cols 56, 57 exist; col 57 is the zero right-pad)
    LOADCOL(XC, 56); COMPUTE(XA, XB, XC, 54);
    LOADCOL(XA, 57); COMPUTE(XB, XC, XA, 55);

#undef LOADCOL
#undef COMPUTE

    __syncthreads();                          // partials cross hf waves

    // drain: wave wv sums the two hf partials for o_local in [wv*32, wv*32+32)
    if (lane < 56) {
        int base = wv * 32;
        float* orow = out + (((size_t)n * 256 + oh * 128 + base) * 56 + h) * 56 + lane;
#pragma unroll 8
        for (int i = 0; i < 32; i++) {
            int v = (int)obuf[0][base + i][lane] + (int)obuf[1][base + i][lane];
            orow[(size_t)i * 3136] = (float)v;
        }
    }
}

extern "C" void kernel_launch(void* const* d_in, const int* in_sizes, int n_in,
                              void* d_out, int out_size, void* d_ws, size_t ws_size,
                              hipStream_t stream) {
    const float* x    = (const float*)d_in[0];
    const float* wsrc = (const float*)d_in[1];
    float* out = (float*)d_out;

    uint32_t* xpad  = (uint32_t*)d_ws;                    // 3.44 MB
    uint32_t* wbits = xpad + XPAD_U32;                    // 18432 u32
    int*      wpop  = (int*)(wbits + 256 * 9 * 8);        // 2304 int

    prep_kernel<<<1097, 256, 0, stream>>>(x, wsrc, xpad, wbits, wpop);
    conv_kernel<<<dim3(HW, N_BATCH, 2), 256, 0, stream>>>(xpad, wbits, wpop, out);
}